// Round 1
// baseline (200.133 us; speedup 1.0000x reference)
//
#include <hip/hip_runtime.h>
#include <hip/hip_bf16.h>

typedef __attribute__((ext_vector_type(8))) short short8;
typedef __attribute__((ext_vector_type(4))) float f32x4;

__device__ __forceinline__ unsigned short f32_bf16(float f) {
  unsigned u = __float_as_uint(f);
  u += 0x7fffu + ((u >> 16) & 1u);           // round-to-nearest-even
  return (unsigned short)(u >> 16);
}

__device__ __forceinline__ short8 cvt8(float4 v0, float4 v1) {
  short8 f;
  f[0] = (short)f32_bf16(v0.x); f[1] = (short)f32_bf16(v0.y);
  f[2] = (short)f32_bf16(v0.z); f[3] = (short)f32_bf16(v0.w);
  f[4] = (short)f32_bf16(v1.x); f[5] = (short)f32_bf16(v1.y);
  f[6] = (short)f32_bf16(v1.z); f[7] = (short)f32_bf16(v1.w);
  return f;
}

// ---- pass 1: z (fp32) -> z_bf16 in workspace --------------------------------
__global__ __launch_bounds__(256) void cvt_bf16_kernel(const float* __restrict__ z,
                                                       unsigned short* __restrict__ zb,
                                                       int n) {
  int i = (blockIdx.x * 256 + threadIdx.x) * 8;
  if (i + 8 <= n) {
    float4 v0 = *(const float4*)(z + i);
    float4 v1 = *(const float4*)(z + i + 4);
    union { unsigned short us[8]; uint4 u4; } r;
    r.us[0] = f32_bf16(v0.x); r.us[1] = f32_bf16(v0.y);
    r.us[2] = f32_bf16(v0.z); r.us[3] = f32_bf16(v0.w);
    r.us[4] = f32_bf16(v1.x); r.us[5] = f32_bf16(v1.y);
    r.us[6] = f32_bf16(v1.z); r.us[7] = f32_bf16(v1.w);
    *(uint4*)(zb + i) = r.u4;
  }
}

// ---- pass 2: fused gather + 3-layer MLP + sigmoid ---------------------------
// One wave handles a tile of 16 edges.
// Layer1: M=16 edges, N=64 (4 ntiles), K=256 (8 chunks of 32), mfma 16x16x32 bf16.
// A-frag layout:  a[j] = A[m=lane&15][k=quad*8+j]      (verified m120)
// B-frag layout:  b[j] = B[k=quad*8+j][n=lane&15]
// C/D layout:     D[row=quad*4+reg][col=lane&15]       (verified m89)
template <bool ZBF>
__global__ __launch_bounds__(256, 2) void lp_main(
    const float* __restrict__ zf, const unsigned short* __restrict__ zb,
    const int* __restrict__ ei,
    const float* __restrict__ W1, const float* __restrict__ b1,
    const float* __restrict__ W2, const float* __restrict__ b2,
    const float* __restrict__ W3, const float* __restrict__ b3,
    float* __restrict__ out, int nEdges) {
  __shared__ unsigned short h1s[4 * 16 * 72];  // per-wave [16 edges][64+pad8] bf16
  __shared__ float h2s[4 * 16 * 33];           // per-wave [16 edges][32+1] fp32

  const int tid = threadIdx.x;
  const int wv  = tid >> 6;
  const int l   = tid & 63;
  const int l15 = l & 15;
  const int q   = l >> 4;

  // ---- per-wave weight fragments (register-resident, loaded once) ----
  short8 w1f[8][4];
#pragma unroll
  for (int c = 0; c < 8; ++c)
#pragma unroll
    for (int t = 0; t < 4; ++t) {
      short8 f;
#pragma unroll
      for (int j = 0; j < 8; ++j)
        f[j] = (short)f32_bf16(W1[(c * 32 + q * 8 + j) * 64 + t * 16 + l15]);
      w1f[c][t] = f;
    }
  short8 w2f[2][2];
#pragma unroll
  for (int c = 0; c < 2; ++c)
#pragma unroll
    for (int t = 0; t < 2; ++t) {
      short8 f;
#pragma unroll
      for (int j = 0; j < 8; ++j)
        f[j] = (short)f32_bf16(W2[(c * 32 + q * 8 + j) * 32 + t * 16 + l15]);
      w2f[c][t] = f;
    }
  float bb1[4];
#pragma unroll
  for (int t = 0; t < 4; ++t) bb1[t] = b1[t * 16 + l15];
  float bb2[2];
#pragma unroll
  for (int t = 0; t < 2; ++t) bb2[t] = b2[t * 16 + l15];
  const float b3v = b3[0];

  unsigned short* h1p = h1s + wv * (16 * 72);
  float* h2p = h2s + wv * (16 * 33);

  const int nTiles = (nEdges + 15) >> 4;
  const int gw = blockIdx.x * 4 + wv;
  const int nw = gridDim.x * 4;

  for (int tile = gw; tile < nTiles; tile += nw) {
    int e = tile * 16 + l15;
    int ec = e < nEdges ? e : (nEdges - 1);
    int src = ei[ec];
    int dst = ei[nEdges + ec];

    // gather A fragments: X[e] = concat(z[src], z[dst]), 256 bf16
    short8 a[8];
    if (ZBF) {
      const unsigned short* rs = zb + (size_t)src * 128;
      const unsigned short* rd = zb + (size_t)dst * 128;
#pragma unroll
      for (int c = 0; c < 4; ++c) {
        a[c]     = *(const short8*)(rs + c * 32 + q * 8);
        a[c + 4] = *(const short8*)(rd + c * 32 + q * 8);
      }
    } else {
      const float* rs = zf + (size_t)src * 128;
      const float* rd = zf + (size_t)dst * 128;
#pragma unroll
      for (int c = 0; c < 4; ++c) {
        int off = c * 32 + q * 8;
        a[c]     = cvt8(*(const float4*)(rs + off), *(const float4*)(rs + off + 4));
        a[c + 4] = cvt8(*(const float4*)(rd + off), *(const float4*)(rd + off + 4));
      }
    }

    // ---- layer 1: [16,256] @ [256,64] + b1 ----
    f32x4 acc[4];
#pragma unroll
    for (int t = 0; t < 4; ++t) {
      acc[t][0] = bb1[t]; acc[t][1] = bb1[t]; acc[t][2] = bb1[t]; acc[t][3] = bb1[t];
    }
#pragma unroll
    for (int c = 0; c < 8; ++c)
#pragma unroll
      for (int t = 0; t < 4; ++t)
        acc[t] = __builtin_amdgcn_mfma_f32_16x16x32_bf16(a[c], w1f[c][t], acc[t], 0, 0, 0);

    // relu -> bf16 -> LDS in [edge][col] layout (stride 72 to dodge conflicts)
#pragma unroll
    for (int t = 0; t < 4; ++t)
#pragma unroll
      for (int r = 0; r < 4; ++r) {
        float v = acc[t][r];
        v = v > 0.f ? v : 0.f;
        h1p[(q * 4 + r) * 72 + t * 16 + l15] = f32_bf16(v);
      }

    // ---- layer 2: [16,64] @ [64,32] + b2 ----
    short8 a2[2];
    a2[0] = *(const short8*)(h1p + l15 * 72 + q * 8);
    a2[1] = *(const short8*)(h1p + l15 * 72 + 32 + q * 8);

    f32x4 acc2[2];
#pragma unroll
    for (int t = 0; t < 2; ++t) {
      acc2[t][0] = bb2[t]; acc2[t][1] = bb2[t]; acc2[t][2] = bb2[t]; acc2[t][3] = bb2[t];
    }
#pragma unroll
    for (int c = 0; c < 2; ++c)
#pragma unroll
      for (int t = 0; t < 2; ++t)
        acc2[t] = __builtin_amdgcn_mfma_f32_16x16x32_bf16(a2[c], w2f[c][t], acc2[t], 0, 0, 0);

#pragma unroll
    for (int t = 0; t < 2; ++t)
#pragma unroll
      for (int r = 0; r < 4; ++r) {
        float v = acc2[t][r];
        h2p[(q * 4 + r) * 33 + t * 16 + l15] = v > 0.f ? v : 0.f;
      }

    // ---- layer 3: [16,32] @ [32,1] + b3, sigmoid ----
    if (l < 16) {
      float d = b3v;
#pragma unroll
      for (int k = 0; k < 32; ++k) d += h2p[l * 33 + k] * W3[k];
      int eo = tile * 16 + l;
      if (eo < nEdges) out[eo] = 1.f / (1.f + __expf(-d));
    }
  }
}

extern "C" void kernel_launch(void* const* d_in, const int* in_sizes, int n_in,
                              void* d_out, int out_size, void* d_ws, size_t ws_size,
                              hipStream_t stream) {
  const float* z  = (const float*)d_in[0];
  const int* ei   = (const int*)d_in[1];
  const float* W1 = (const float*)d_in[2];
  const float* b1 = (const float*)d_in[3];
  const float* W2 = (const float*)d_in[4];
  const float* b2 = (const float*)d_in[5];
  const float* W3 = (const float*)d_in[6];
  const float* b3 = (const float*)d_in[7];
  float* out = (float*)d_out;

  const int nZ = in_sizes[0];          // n_nodes * 128
  const int nEdges = in_sizes[1] / 2;  // edge_index is [2, E]

  const bool useWs = ws_size >= (size_t)nZ * sizeof(unsigned short);
  if (useWs) {
    unsigned short* zb = (unsigned short*)d_ws;
    int nThr = nZ / 8;
    cvt_bf16_kernel<<<(nThr + 255) / 256, 256, 0, stream>>>(z, zb, nZ);
    lp_main<true><<<1024, 256, 0, stream>>>(z, zb, ei, W1, b1, W2, b2, W3, b3, out, nEdges);
  } else {
    lp_main<false><<<1024, 256, 0, stream>>>(z, nullptr, ei, W1, b1, W2, b2, W3, b3, out, nEdges);
  }
}